// Round 1
// baseline (851.995 us; speedup 1.0000x reference)
//
#include <hip/hip_runtime.h>
#include <stdint.h>

typedef short bf16x8 __attribute__((ext_vector_type(8)));
typedef float f32x4 __attribute__((ext_vector_type(4)));
typedef unsigned short u16x4 __attribute__((ext_vector_type(4)));
typedef unsigned short ushort_t;

__device__ __forceinline__ float bf2f(unsigned short u) {
    union { unsigned int i; float f; } v; v.i = ((unsigned int)u) << 16; return v.f;
}
__device__ __forceinline__ unsigned short f2bf(float f) {
    union { float f; unsigned int i; } v; v.f = f;
    unsigned int r = (v.i + 0x7FFFu + ((v.i >> 16) & 1u)) >> 16;
    return (unsigned short)r;
}

// Dtype-polymorphic loaders. F32=true: buffers are float32. F32=false: bf16.
template <bool F32> struct LD;
template <> struct LD<false> {
    static __device__ __forceinline__ float s(const void* p, size_t i) {
        return bf2f(((const ushort_t*)p)[i]);
    }
    static __device__ __forceinline__ bf16x8 v8(const void* p, size_t i) {
        return *reinterpret_cast<const bf16x8*>((const ushort_t*)p + i);
    }
};
template <> struct LD<true> {
    static __device__ __forceinline__ float s(const void* p, size_t i) {
        return ((const float*)p)[i];
    }
    static __device__ __forceinline__ bf16x8 v8(const void* p, size_t i) {
        const float* f = (const float*)p + i;
        float4 a = *reinterpret_cast<const float4*>(f);
        float4 b = *reinterpret_cast<const float4*>(f + 4);
        bf16x8 r;
        r[0] = (short)f2bf(a.x); r[1] = (short)f2bf(a.y);
        r[2] = (short)f2bf(a.z); r[3] = (short)f2bf(a.w);
        r[4] = (short)f2bf(b.x); r[5] = (short)f2bf(b.y);
        r[6] = (short)f2bf(b.z); r[7] = (short)f2bf(b.w);
        return r;
    }
};

// ---------------- K0: dtype probe ----------------
__global__ __launch_bounds__(64) void kprobe(const ushort_t* __restrict__ pos, int* __restrict__ dt) {
    float v = bf2f(pos[2 * threadIdx.x]);
    bool sane = (v >= 0.0f) && (v <= 1.0f);
    unsigned long long b = __ballot(sane);
    if (threadIdx.x == 0) dt[0] = (b == ~0ULL) ? 1 : 0;  // 1 = bf16, 0 = f32
}

// ---------------- K1: global max of pos per coordinate ----------------
template <bool F32>
static __device__ __forceinline__ void kpos_body(const void* pos, int* pmax, float* s0, float* s1) {
    int p = blockIdx.x * 256 + threadIdx.x;
    s0[threadIdx.x] = LD<F32>::s(pos, 2 * (size_t)p);
    s1[threadIdx.x] = LD<F32>::s(pos, 2 * (size_t)p + 1);
    __syncthreads();
    for (int off = 128; off > 0; off >>= 1) {
        if (threadIdx.x < (unsigned)off) {
            s0[threadIdx.x] = fmaxf(s0[threadIdx.x], s0[threadIdx.x + off]);
            s1[threadIdx.x] = fmaxf(s1[threadIdx.x], s1[threadIdx.x + off]);
        }
        __syncthreads();
    }
    if (threadIdx.x == 0) {
        atomicMax(&pmax[0], __float_as_int(s0[0]));
        atomicMax(&pmax[1], __float_as_int(s1[0]));
    }
}
__global__ __launch_bounds__(256) void kpos_max(const int* __restrict__ dt, const void* __restrict__ pos,
                                                int* __restrict__ pmax) {
    __shared__ float s0[256], s1[256];
    if (dt[0]) kpos_body<false>(pos, pmax, s0, s1);
    else       kpos_body<true>(pos, pmax, s0, s1);
}

// ---------------- K2: per-key bias tb[p][h] = pos_n . pos_w + maskterm ----------------
template <bool F32>
static __device__ __forceinline__ void ktb_body(const void* pos, const void* pos_w, const int* mask,
                                                const int* pmax, float* tb) {
    int p = blockIdx.x * 256 + threadIdx.x;
    float inv0 = 1.0f / __int_as_float(pmax[0]);
    float inv1 = 1.0f / __int_as_float(pmax[1]);
    float x0 = LD<F32>::s(pos, 2 * (size_t)p) * inv0;
    float x1 = LD<F32>::s(pos, 2 * (size_t)p + 1) * inv1;
    float mterm = mask[p] ? 0.0f : -100.0f;
#pragma unroll
    for (int h = 0; h < 8; h++)
        tb[p * 8 + h] = x0 * LD<F32>::s(pos_w, h) + x1 * LD<F32>::s(pos_w, 8 + h) + mterm;
}
__global__ __launch_bounds__(256) void ktb(const int* __restrict__ dt, const void* __restrict__ pos,
                                           const void* __restrict__ pos_w, const int* __restrict__ mask,
                                           const int* __restrict__ pmax, float* __restrict__ tb) {
    if (dt[0]) ktb_body<false>(pos, pos_w, mask, pmax, tb);
    else       ktb_body<true>(pos, pos_w, mask, pmax, tb);
}

// ---------------- Kb: biases -> f32 (so the hot kernels are dtype-free) ----------------
__global__ __launch_bounds__(256) void kbias(const int* __restrict__ dt, const void* __restrict__ qkv_b,
                                             const void* __restrict__ proj_b,
                                             float* __restrict__ qb, float* __restrict__ pb) {
    int i = blockIdx.x * 256 + threadIdx.x;
    if (dt[0]) {
        if (i < 1536) qb[i] = bf2f(((const ushort_t*)qkv_b)[i]);
        if (i < 512)  pb[i] = bf2f(((const ushort_t*)proj_b)[i]);
    } else {
        if (i < 1536) qb[i] = ((const float*)qkv_b)[i];
        if (i < 512)  pb[i] = ((const float*)proj_b)[i];
    }
}

// ---------------- Kf: feat -> bf16 once (kills 8x re-conversion in kattn) ----------------
template <bool F32>
static __device__ __forceinline__ void kfeat_body(const void* feat, ushort_t* featb) {
    for (size_t t = (size_t)blockIdx.x * 256 + threadIdx.x; t < 4194304; t += (size_t)gridDim.x * 256) {
        *reinterpret_cast<bf16x8*>(featb + t * 8) = LD<F32>::v8(feat, t * 8);
    }
}
__global__ __launch_bounds__(256) void kfeat(const int* __restrict__ dt, const void* __restrict__ feat,
                                             ushort_t* __restrict__ featb) {
    if (dt[0]) kfeat_body<false>(feat, featb);
    else       kfeat_body<true>(feat, featb);
}

// ---------------- Kt: transpose (R x C -> C x R) into bf16, 64x64 tiles ----------------
template <bool F32>
static __device__ __forceinline__ void ktrans_body(const void* src, ushort_t* dst, int R, int C,
                                                   ushort_t* tile /*64x65*/) {
    int nbc = C >> 6;
    int rb = (blockIdx.x / nbc) << 6;
    int cb = (blockIdx.x % nbc) << 6;
    for (int i = threadIdx.x; i < 4096; i += 256) {
        int r = i >> 6, c = i & 63;
        tile[r * 65 + c] = f2bf(LD<F32>::s(src, (size_t)(rb + r) * C + cb + c));
    }
    __syncthreads();
    for (int i = threadIdx.x; i < 4096; i += 256) {
        int rr = i & 63, cc = i >> 6;
        dst[(size_t)(cb + cc) * R + rb + rr] = tile[rr * 65 + cc];
    }
}
__global__ __launch_bounds__(256) void ktrans(const int* __restrict__ dt, const void* __restrict__ src,
                                              ushort_t* __restrict__ dst, int R, int C) {
    __shared__ ushort_t tile[64 * 65];
    if (dt[0]) ktrans_body<false>(src, dst, R, C, tile);
    else       ktrans_body<true>(src, dst, R, C, tile);
}

// ---------------- K3: fused QKV projection + attention ----------------
// 512 threads = 8 waves (2 waves/SIMD for latency hiding), 32 rows/wave.
// Block decode keeps all 8 heads of a cluster on ONE XCD in the SAME occupancy
// round (1 block/CU, 8 rounds): feat tile is fetched into that XCD's L2 once.
template <bool F32>
static __device__ __forceinline__ void kattn_body(const void* feat, const ushort_t* qkv_wt,
                                                  const float* qb, const float* tb, ushort_t* xout,
                                                  ushort_t* sQ, ushort_t* sK, ushort_t* sVt,
                                                  ushort_t* sP, float* stb) {
    const int tid = threadIdx.x;
    const int lane = tid & 63;
    const int wave = tid >> 6;   // 0..7
    const int quad = lane >> 4;
    const int l15 = lane & 15;

    // XCD-aware decode: bx = xcd + 8*(32*round + slot); slot = 8*(cluster-within-round) + head
    const int bx = blockIdx.x;
    const int xcd = bx & 7;
    const int jj = bx >> 3;          // 0..255
    const int rr = jj >> 5;          // round 0..7
    const int ss = jj & 31;          // slot within round
    const int kc = xcd * 32 + rr * 4 + (ss >> 3);
    const int h = ss & 7;

    if (tid < 256) stb[tid] = tb[(size_t)(kc * 256 + tid) * 8 + h];

    // ---- Phase A: Q/K/V = feat[kc] @ qkv_w slices ----
    f32x4 acc[3][2][4];
#pragma unroll
    for (int mat = 0; mat < 3; mat++)
#pragma unroll
        for (int rt = 0; rt < 2; rt++)
#pragma unroll
            for (int ct = 0; ct < 4; ct++) {
                f32x4 z = {0.0f, 0.0f, 0.0f, 0.0f};
                acc[mat][rt][ct] = z;
            }

    const size_t fbase = (size_t)(kc * 256) * 512;
    const int mrow = wave * 32 + l15;

    for (int c = 0; c < 16; c++) {
        bf16x8 af[2];
#pragma unroll
        for (int rt = 0; rt < 2; rt++)
            af[rt] = LD<F32>::v8(feat, fbase + (size_t)(mrow + rt * 16) * 512 + c * 32 + quad * 8);
#pragma unroll
        for (int mat = 0; mat < 3; mat++) {
#pragma unroll
            for (int ct = 0; ct < 4; ct++) {
                int n = mat * 512 + h * 64 + ct * 16 + l15;
                bf16x8 bfr = *reinterpret_cast<const bf16x8*>(qkv_wt + (size_t)n * 512 + c * 32 + quad * 8);
#pragma unroll
                for (int rt = 0; rt < 2; rt++)
                    acc[mat][rt][ct] =
                        __builtin_amdgcn_mfma_f32_16x16x32_bf16(af[rt], bfr, acc[mat][rt][ct], 0, 0, 0);
            }
        }
    }

    // Epilogue: bias, scale Q, store Q/K row-major and V transposed into LDS
#pragma unroll
    for (int ct = 0; ct < 4; ct++) {
        int hd_ = ct * 16 + l15;
        int nn = h * 64 + hd_;
        float bq = qb[nn];
        float bk = qb[512 + nn];
        float bv = qb[1024 + nn];
#pragma unroll
        for (int rt = 0; rt < 2; rt++) {
            int m0 = wave * 32 + rt * 16 + quad * 4;
            u16x4 vp;
#pragma unroll
            for (int r = 0; r < 4; r++) {
                sQ[(m0 + r) * 72 + hd_] = f2bf((acc[0][rt][ct][r] + bq) * 0.125f);
                sK[(m0 + r) * 72 + hd_] = f2bf(acc[1][rt][ct][r] + bk);
                vp[r] = f2bf(acc[2][rt][ct][r] + bv);
            }
            *reinterpret_cast<u16x4*>(&sVt[hd_ * 264 + m0]) = vp;
        }
    }
    __syncthreads();

    // ---- Phase B: S = Q K^T + bias, exp, P@V, normalize ----
    bf16x8 aQ[2][2];
#pragma unroll
    for (int rt = 0; rt < 2; rt++)
#pragma unroll
        for (int s = 0; s < 2; s++)
            aQ[rt][s] = *reinterpret_cast<const bf16x8*>(
                &sQ[(wave * 32 + rt * 16 + l15) * 72 + s * 32 + quad * 8]);

    f32x4 accO[2][4];
    float rs[2][4];
#pragma unroll
    for (int rt = 0; rt < 2; rt++)
#pragma unroll
        for (int ct = 0; ct < 4; ct++) {
            f32x4 z = {0.0f, 0.0f, 0.0f, 0.0f};
            accO[rt][ct] = z;
            rs[rt][ct] = 0.0f;  // rs[rt][r]
        }

    ushort_t* sPw = sP + wave * (32 * 72);

    for (int jb = 0; jb < 4; jb++) {
        int kb = jb * 64;
        bf16x8 bK[4][2];
#pragma unroll
        for (int ctk = 0; ctk < 4; ctk++)
#pragma unroll
            for (int s = 0; s < 2; s++)
                bK[ctk][s] = *reinterpret_cast<const bf16x8*>(
                    &sK[(kb + ctk * 16 + l15) * 72 + s * 32 + quad * 8]);

#pragma unroll
        for (int ctk = 0; ctk < 4; ctk++) {
            float tcol = stb[kb + ctk * 16 + l15];
#pragma unroll
            for (int rt = 0; rt < 2; rt++) {
                f32x4 sa = {0.0f, 0.0f, 0.0f, 0.0f};
                sa = __builtin_amdgcn_mfma_f32_16x16x32_bf16(aQ[rt][0], bK[ctk][0], sa, 0, 0, 0);
                sa = __builtin_amdgcn_mfma_f32_16x16x32_bf16(aQ[rt][1], bK[ctk][1], sa, 0, 0, 0);
                int rl0 = rt * 16 + quad * 4;
#pragma unroll
                for (int r = 0; r < 4; r++) {
                    float pexp = __expf(sa[r] + tcol);  // no max-sub: |S|<~5, masked ~ -100, safe in f32
                    rs[rt][r] += pexp;
                    sPw[(rl0 + r) * 72 + ctk * 16 + l15] = f2bf(pexp);
                }
            }
        }

        // P @ V over this key block (wave-private P, same-wave LDS ordering, no barrier)
#pragma unroll
        for (int s = 0; s < 2; s++) {
            bf16x8 aP[2];
#pragma unroll
            for (int rt = 0; rt < 2; rt++)
                aP[rt] = *reinterpret_cast<const bf16x8*>(
                    &sPw[(rt * 16 + l15) * 72 + s * 32 + quad * 8]);
#pragma unroll
            for (int ct = 0; ct < 4; ct++) {
                bf16x8 bV = *reinterpret_cast<const bf16x8*>(
                    &sVt[(ct * 16 + l15) * 264 + kb + s * 32 + quad * 8]);
#pragma unroll
                for (int rt = 0; rt < 2; rt++)
                    accO[rt][ct] =
                        __builtin_amdgcn_mfma_f32_16x16x32_bf16(aP[rt], bV, accO[rt][ct], 0, 0, 0);
            }
        }
    }

    // Row sums: butterfly over the 16 lanes sharing a quad
    float inv_[2][4];
#pragma unroll
    for (int rt = 0; rt < 2; rt++)
#pragma unroll
        for (int r = 0; r < 4; r++) {
            float v = rs[rt][r];
            v += __shfl_xor(v, 1, 64);
            v += __shfl_xor(v, 2, 64);
            v += __shfl_xor(v, 4, 64);
            v += __shfl_xor(v, 8, 64);
            inv_[rt][r] = 1.0f / v;
        }

#pragma unroll
    for (int rt = 0; rt < 2; rt++)
#pragma unroll
        for (int ct = 0; ct < 4; ct++)
#pragma unroll
            for (int r = 0; r < 4; r++) {
                int m = wave * 32 + rt * 16 + quad * 4 + r;
                xout[((size_t)(kc * 256 + m)) * 512 + h * 64 + ct * 16 + l15] =
                    f2bf(accO[rt][ct][r] * inv_[rt][r]);
            }
}
__global__ __launch_bounds__(512, 2) void kattn_bf(const ushort_t* __restrict__ featb,
                                                   const ushort_t* __restrict__ qkv_wt,
                                                   const float* __restrict__ qb,
                                                   const float* __restrict__ tb, ushort_t* __restrict__ xout) {
    __shared__ ushort_t sQ[256 * 72];
    __shared__ ushort_t sK[256 * 72];
    __shared__ ushort_t sVt[64 * 264];
    __shared__ ushort_t sP[8 * 32 * 72];
    __shared__ float stb[256];
    kattn_body<false>(featb, qkv_wt, qb, tb, xout, sQ, sK, sVt, sP, stb);
}
__global__ __launch_bounds__(512, 2) void kattn_dyn(const int* __restrict__ dt, const void* __restrict__ feat,
                                                    const ushort_t* __restrict__ qkv_wt,
                                                    const float* __restrict__ qb,
                                                    const float* __restrict__ tb, ushort_t* __restrict__ xout) {
    __shared__ ushort_t sQ[256 * 72];
    __shared__ ushort_t sK[256 * 72];
    __shared__ ushort_t sVt[64 * 264];
    __shared__ ushort_t sP[8 * 32 * 72];
    __shared__ float stb[256];
    if (dt[0]) kattn_body<false>(feat, qkv_wt, qb, tb, xout, sQ, sK, sVt, sP, stb);
    else       kattn_body<true>(feat, qkv_wt, qb, tb, xout, sQ, sK, sVt, sP, stb);
}

// ---------------- K4: out = x @ proj_w + proj_b ----------------
// Block decode keeps the 4 col-blocks sharing an x row-panel on the same XCD.
template <bool F32>
static __device__ __forceinline__ void kproj_body(const ushort_t* x, const ushort_t* proj_wt,
                                                  const float* pb, void* out) {
    const int tid = threadIdx.x;
    const int lane = tid & 63;
    const int wave = tid >> 6;
    const int quad = lane >> 4;
    const int l15 = lane & 15;
    const int rowb = (blockIdx.x & 255) * 256 + wave * 64;
    const int colb = (blockIdx.x >> 8) * 128;

    f32x4 acc[4][8];
#pragma unroll
    for (int rt = 0; rt < 4; rt++)
#pragma unroll
        for (int ct = 0; ct < 8; ct++) {
            f32x4 z = {0.0f, 0.0f, 0.0f, 0.0f};
            acc[rt][ct] = z;
        }

    for (int c = 0; c < 16; c++) {
        bf16x8 af[4];
#pragma unroll
        for (int rt = 0; rt < 4; rt++) {
            int m = rowb + rt * 16 + l15;
            af[rt] = *reinterpret_cast<const bf16x8*>(x + (size_t)m * 512 + c * 32 + quad * 8);
        }
#pragma unroll
        for (int ct = 0; ct < 8; ct++) {
            int n = colb + ct * 16 + l15;
            bf16x8 bfr = *reinterpret_cast<const bf16x8*>(proj_wt + (size_t)n * 512 + c * 32 + quad * 8);
#pragma unroll
            for (int rt = 0; rt < 4; rt++)
                acc[rt][ct] = __builtin_amdgcn_mfma_f32_16x16x32_bf16(af[rt], bfr, acc[rt][ct], 0, 0, 0);
        }
    }

#pragma unroll
    for (int ct = 0; ct < 8; ct++) {
        int n = colb + ct * 16 + l15;
        float bias = pb[n];
#pragma unroll
        for (int rt = 0; rt < 4; rt++)
#pragma unroll
            for (int r = 0; r < 4; r++) {
                int m = rowb + rt * 16 + quad * 4 + r;
                float v = acc[rt][ct][r] + bias;
                if (F32) ((float*)out)[(size_t)m * 512 + n] = v;
                else     ((ushort_t*)out)[(size_t)m * 512 + n] = f2bf(v);
            }
    }
}
__global__ __launch_bounds__(256, 2) void kproj(const int* __restrict__ dt, const ushort_t* __restrict__ x,
                                                const ushort_t* __restrict__ proj_wt,
                                                const float* __restrict__ pb, void* __restrict__ out) {
    if (dt[0]) kproj_body<false>(x, proj_wt, pb, out);
    else       kproj_body<true>(x, proj_wt, pb, out);
}

extern "C" void kernel_launch(void* const* d_in, const int* in_sizes, int n_in,
                              void* d_out, int out_size, void* d_ws, size_t ws_size,
                              hipStream_t stream) {
    (void)in_sizes; (void)n_in; (void)out_size;
    const void* pos    = d_in[0];
    const void* feat   = d_in[1];
    const void* qkv_w  = d_in[2];
    const void* qkv_b  = d_in[3];
    const void* pos_w  = d_in[4];
    // d_in[5] = pos_b: softmax-invariant (constant per attention row), intentionally unused
    const void* proj_w = d_in[6];
    const void* proj_b = d_in[7];
    const int* mask    = (const int*)d_in[8];

    char* ws = (char*)d_ws;
    int* pmax         = (int*)ws;                           // ints 0,1
    int* dtf          = (int*)ws + 2;                       // int 2: dtype flag
    float* qb         = (float*)(ws + 256);                 // 1536 f32
    float* pb         = (float*)(ws + 256 + 6144);          // 512 f32
    float* tb         = (float*)(ws + 16384);               // 65536*8 f32 = 2 MB
    ushort_t* qkv_wt  = (ushort_t*)(ws + 16384 + 2097152);  // 1536x512 bf16
    ushort_t* proj_wt = qkv_wt + 786432;                    // 512x512 bf16
    ushort_t* x       = proj_wt + 262144;                   // 65536x512 bf16 = 64 MB
    ushort_t* featb   = x + 33554432;                       // 65536x512 bf16 = 64 MB
    const size_t NEED = 16384 + 2097152 + 1572864 + 524288 + 67108864 + 67108864;
    const bool big = ws_size >= NEED;

    (void)hipMemsetAsync(ws, 0, 16, stream);
    kprobe<<<1, 64, 0, stream>>>((const ushort_t*)pos, dtf);
    kpos_max<<<256, 256, 0, stream>>>(dtf, pos, pmax);
    ktb<<<256, 256, 0, stream>>>(dtf, pos, pos_w, mask, pmax, tb);
    kbias<<<6, 256, 0, stream>>>(dtf, qkv_b, proj_b, qb, pb);
    ktrans<<<192, 256, 0, stream>>>(dtf, qkv_w, qkv_wt, 512, 1536);
    ktrans<<<64, 256, 0, stream>>>(dtf, proj_w, proj_wt, 512, 512);
    if (big) {
        kfeat<<<2048, 256, 0, stream>>>(dtf, feat, featb);
        kattn_bf<<<2048, 512, 0, stream>>>(featb, qkv_wt, qb, tb, x);
    } else {
        kattn_dyn<<<2048, 512, 0, stream>>>(dtf, feat, qkv_wt, qb, tb, x);
    }
    kproj<<<1024, 256, 0, stream>>>(dtf, x, proj_wt, pb, d_out);
}

// Round 2
// 582.062 us; speedup vs baseline: 1.4638x; 1.4638x over previous
//
#include <hip/hip_runtime.h>
#include <stdint.h>

typedef short bf16x8 __attribute__((ext_vector_type(8)));
typedef float f32x4 __attribute__((ext_vector_type(4)));
typedef unsigned short u16x4 __attribute__((ext_vector_type(4)));
typedef unsigned short ushort_t;

__device__ __forceinline__ float bf2f(unsigned short u) {
    union { unsigned int i; float f; } v; v.i = ((unsigned int)u) << 16; return v.f;
}
__device__ __forceinline__ unsigned short f2bf(float f) {
    union { float f; unsigned int i; } v; v.f = f;
    unsigned int r = (v.i + 0x7FFFu + ((v.i >> 16) & 1u)) >> 16;
    return (unsigned short)r;
}

// async global->LDS, 16B per lane; LDS dest = wave-uniform base + lane*16
__device__ __forceinline__ void gload_lds16(const void* g, void* l) {
    __builtin_amdgcn_global_load_lds(
        (const __attribute__((address_space(1))) void*)g,
        (__attribute__((address_space(3))) void*)l, 16, 0, 0);
}

// Dtype-polymorphic loaders. F32=true: buffers are float32. F32=false: bf16.
template <bool F32> struct LD;
template <> struct LD<false> {
    static __device__ __forceinline__ float s(const void* p, size_t i) {
        return bf2f(((const ushort_t*)p)[i]);
    }
    static __device__ __forceinline__ bf16x8 v8(const void* p, size_t i) {
        return *reinterpret_cast<const bf16x8*>((const ushort_t*)p + i);
    }
};
template <> struct LD<true> {
    static __device__ __forceinline__ float s(const void* p, size_t i) {
        return ((const float*)p)[i];
    }
    static __device__ __forceinline__ bf16x8 v8(const void* p, size_t i) {
        const float* f = (const float*)p + i;
        float4 a = *reinterpret_cast<const float4*>(f);
        float4 b = *reinterpret_cast<const float4*>(f + 4);
        bf16x8 r;
        r[0] = (short)f2bf(a.x); r[1] = (short)f2bf(a.y);
        r[2] = (short)f2bf(a.z); r[3] = (short)f2bf(a.w);
        r[4] = (short)f2bf(b.x); r[5] = (short)f2bf(b.y);
        r[6] = (short)f2bf(b.z); r[7] = (short)f2bf(b.w);
        return r;
    }
};

// ---------------- K0: dtype probe ----------------
__global__ __launch_bounds__(64) void kprobe(const ushort_t* __restrict__ pos, int* __restrict__ dt) {
    float v = bf2f(pos[2 * threadIdx.x]);
    bool sane = (v >= 0.0f) && (v <= 1.0f);
    unsigned long long b = __ballot(sane);
    if (threadIdx.x == 0) dt[0] = (b == ~0ULL) ? 1 : 0;  // 1 = bf16, 0 = f32
}

// ---------------- K1: global max of pos per coordinate ----------------
template <bool F32>
static __device__ __forceinline__ void kpos_body(const void* pos, int* pmax, float* s0, float* s1) {
    int p = blockIdx.x * 256 + threadIdx.x;
    s0[threadIdx.x] = LD<F32>::s(pos, 2 * (size_t)p);
    s1[threadIdx.x] = LD<F32>::s(pos, 2 * (size_t)p + 1);
    __syncthreads();
    for (int off = 128; off > 0; off >>= 1) {
        if (threadIdx.x < (unsigned)off) {
            s0[threadIdx.x] = fmaxf(s0[threadIdx.x], s0[threadIdx.x + off]);
            s1[threadIdx.x] = fmaxf(s1[threadIdx.x], s1[threadIdx.x + off]);
        }
        __syncthreads();
    }
    if (threadIdx.x == 0) {
        atomicMax(&pmax[0], __float_as_int(s0[0]));
        atomicMax(&pmax[1], __float_as_int(s1[0]));
    }
}
__global__ __launch_bounds__(256) void kpos_max(const int* __restrict__ dt, const void* __restrict__ pos,
                                                int* __restrict__ pmax) {
    __shared__ float s0[256], s1[256];
    if (dt[0]) kpos_body<false>(pos, pmax, s0, s1);
    else       kpos_body<true>(pos, pmax, s0, s1);
}

// ---------------- K2: per-key bias tb[p][h] = pos_n . pos_w + maskterm ----------------
template <bool F32>
static __device__ __forceinline__ void ktb_body(const void* pos, const void* pos_w, const int* mask,
                                                const int* pmax, float* tb) {
    int p = blockIdx.x * 256 + threadIdx.x;
    float inv0 = 1.0f / __int_as_float(pmax[0]);
    float inv1 = 1.0f / __int_as_float(pmax[1]);
    float x0 = LD<F32>::s(pos, 2 * (size_t)p) * inv0;
    float x1 = LD<F32>::s(pos, 2 * (size_t)p + 1) * inv1;
    float mterm = mask[p] ? 0.0f : -100.0f;
#pragma unroll
    for (int h = 0; h < 8; h++)
        tb[p * 8 + h] = x0 * LD<F32>::s(pos_w, h) + x1 * LD<F32>::s(pos_w, 8 + h) + mterm;
}
__global__ __launch_bounds__(256) void ktb(const int* __restrict__ dt, const void* __restrict__ pos,
                                           const void* __restrict__ pos_w, const int* __restrict__ mask,
                                           const int* __restrict__ pmax, float* __restrict__ tb) {
    if (dt[0]) ktb_body<false>(pos, pos_w, mask, pmax, tb);
    else       ktb_body<true>(pos, pos_w, mask, pmax, tb);
}

// ---------------- Kb: biases -> f32 ----------------
__global__ __launch_bounds__(256) void kbias(const int* __restrict__ dt, const void* __restrict__ qkv_b,
                                             const void* __restrict__ proj_b,
                                             float* __restrict__ qb, float* __restrict__ pb) {
    int i = blockIdx.x * 256 + threadIdx.x;
    if (dt[0]) {
        if (i < 1536) qb[i] = bf2f(((const ushort_t*)qkv_b)[i]);
        if (i < 512)  pb[i] = bf2f(((const ushort_t*)proj_b)[i]);
    } else {
        if (i < 1536) qb[i] = ((const float*)qkv_b)[i];
        if (i < 512)  pb[i] = ((const float*)proj_b)[i];
    }
}

// ---------------- Kf: feat -> bf16 once ----------------
template <bool F32>
static __device__ __forceinline__ void kfeat_body(const void* feat, ushort_t* featb) {
    for (size_t t = (size_t)blockIdx.x * 256 + threadIdx.x; t < 4194304; t += (size_t)gridDim.x * 256) {
        *reinterpret_cast<bf16x8*>(featb + t * 8) = LD<F32>::v8(feat, t * 8);
    }
}
__global__ __launch_bounds__(256) void kfeat(const int* __restrict__ dt, const void* __restrict__ feat,
                                             ushort_t* __restrict__ featb) {
    if (dt[0]) kfeat_body<false>(feat, featb);
    else       kfeat_body<true>(feat, featb);
}

// ---------------- Kt: transpose (R x C -> C x R) into bf16, 64x64 tiles ----------------
template <bool F32>
static __device__ __forceinline__ void ktrans_body(const void* src, ushort_t* dst, int R, int C,
                                                   ushort_t* tile /*64x65*/) {
    int nbc = C >> 6;
    int rb = (blockIdx.x / nbc) << 6;
    int cb = (blockIdx.x % nbc) << 6;
    for (int i = threadIdx.x; i < 4096; i += 256) {
        int r = i >> 6, c = i & 63;
        tile[r * 65 + c] = f2bf(LD<F32>::s(src, (size_t)(rb + r) * C + cb + c));
    }
    __syncthreads();
    for (int i = threadIdx.x; i < 4096; i += 256) {
        int rr = i & 63, cc = i >> 6;
        dst[(size_t)(cb + cc) * R + rb + rr] = tile[rr * 65 + cc];
    }
}
__global__ __launch_bounds__(256) void ktrans(const int* __restrict__ dt, const void* __restrict__ src,
                                              ushort_t* __restrict__ dst, int R, int C) {
    __shared__ ushort_t tile[64 * 65];
    if (dt[0]) ktrans_body<false>(src, dst, R, C, tile);
    else       ktrans_body<true>(src, dst, R, C, tile);
}

// ---------------- K3: fused QKV projection + attention ----------------
// 512 threads = 8 waves. Phase A: qkv_wt slice (192 rows x 512) is staged
// through LDS via global_load_lds, double-buffered, so each W-byte crosses
// L1/L2 ONCE per block (was 8x per-wave global gathers -> L1/L2 storm).
// Wave tile 64x96 (acc[4][6]). Phase B (attention) unchanged from v1.
template <bool F32>
static __device__ __forceinline__ void kattn_body(const void* feat, const ushort_t* qkv_wt,
                                                  const float* qb, const float* tb, ushort_t* xout,
                                                  ushort_t* sQ, ushort_t* sK, ushort_t* sVt,
                                                  ushort_t* sP, float* stb) {
    const int tid = threadIdx.x;
    const int lane = tid & 63;
    const int wave = tid >> 6;   // 0..7
    const int quad = lane >> 4;
    const int l15 = lane & 15;

    // XCD-aware decode: all 8 heads of a cluster co-resident on one XCD round
    const int bx = blockIdx.x;
    const int xcd = bx & 7;
    const int jj = bx >> 3;
    const int rr = jj >> 5;
    const int ss = jj & 31;
    const int kc = xcd * 32 + rr * 4 + (ss >> 3);
    const int h = ss & 7;

    if (tid < 256) stb[tid] = tb[(size_t)(kc * 256 + tid) * 8 + h];

    ushort_t* sW = sP;  // Phase A W-staging aliases the (Phase-B-only) sP region
    char* ldsW = (char*)sW;

    // staging tasks: 768 = 192 rows x 4 chunks(16B). task t -> lc=t>>2, ch=t&3.
    // wave w covers tasks w*64+lane; waves 0..3 also 512 + w*64 + lane.
    const int t1 = wave * 64 + lane;
    const int t2 = 512 + t1;
    const int lc1 = t1 >> 2, ch1 = t1 & 3;
    const int lc2 = t2 >> 2, ch2 = t2 & 3;
    const ushort_t* g1 = qkv_wt + (size_t)((lc1 >> 6) * 512 + h * 64 + (lc1 & 63)) * 512 + ch1 * 8;
    const ushort_t* g2 = qkv_wt + (size_t)((lc2 >> 6) * 512 + h * 64 + (lc2 & 63)) * 512 + ch2 * 8;

    const int wrow = (wave >> 1) * 64;   // 4 row groups
    const int wcol = (wave & 1) * 96;    // 2 col groups (of 192 = 3 mats x 64)
    const int fcol = quad * 8;

    f32x4 acc[4][6];
#pragma unroll
    for (int rt = 0; rt < 4; rt++)
#pragma unroll
        for (int ct = 0; ct < 6; ct++) {
            f32x4 z = {0.0f, 0.0f, 0.0f, 0.0f};
            acc[rt][ct] = z;
        }

    const size_t fbase = (size_t)(kc * 256) * 512;

    // prologue: stage slice 0 into buf0
    gload_lds16(g1, ldsW + wave * 1024);
    if (wave < 4) gload_lds16(g2, ldsW + 8192 + wave * 1024);
    __syncthreads();

#pragma unroll 2
    for (int c = 0; c < 16; c++) {
        const int cb = (c & 1) * 6144;             // u16 offset of current buf
        const int nbB = ((c + 1) & 1) * 12288;     // byte offset of next buf
        if (c < 15) {
            gload_lds16(g1 + (c + 1) * 32, ldsW + nbB + wave * 1024);
            if (wave < 4) gload_lds16(g2 + (c + 1) * 32, ldsW + nbB + 8192 + wave * 1024);
        }
        bf16x8 af[4];
#pragma unroll
        for (int rt = 0; rt < 4; rt++)
            af[rt] = LD<F32>::v8(feat, fbase + (size_t)(wrow + rt * 16 + l15) * 512 + c * 32 + fcol);
        bf16x8 bw[6];
#pragma unroll
        for (int ct = 0; ct < 6; ct++)
            bw[ct] = *reinterpret_cast<const bf16x8*>(sW + cb + (wcol + ct * 16 + l15) * 32 + fcol);
#pragma unroll
        for (int ct = 0; ct < 6; ct++)
#pragma unroll
            for (int rt = 0; rt < 4; rt++)
                acc[rt][ct] = __builtin_amdgcn_mfma_f32_16x16x32_bf16(af[rt], bw[ct], acc[rt][ct], 0, 0, 0);
        __syncthreads();
    }

    // Epilogue: bias, scale Q, store Q/K row-major and V transposed into LDS
#pragma unroll
    for (int ct = 0; ct < 6; ct++) {
        const int lcb = wcol + ct * 16;      // 16-aligned segment within [0,192)
        const int mat = lcb >> 6;            // wave-uniform: 0=Q 1=K 2=V
        const int col = (lcb & 63) + l15;    // 0..63
        const float bias = qb[mat * 512 + h * 64 + col];
#pragma unroll
        for (int rt = 0; rt < 4; rt++) {
            const int m0 = wrow + rt * 16 + quad * 4;
            if (mat == 0) {
#pragma unroll
                for (int r = 0; r < 4; r++)
                    sQ[(m0 + r) * 72 + col] = f2bf((acc[rt][ct][r] + bias) * 0.125f);
            } else if (mat == 1) {
#pragma unroll
                for (int r = 0; r < 4; r++)
                    sK[(m0 + r) * 72 + col] = f2bf(acc[rt][ct][r] + bias);
            } else {
                u16x4 vp;
#pragma unroll
                for (int r = 0; r < 4; r++) vp[r] = f2bf(acc[rt][ct][r] + bias);
                *reinterpret_cast<u16x4*>(&sVt[col * 264 + m0]) = vp;
            }
        }
    }
    __syncthreads();

    // ---- Phase B: S = Q K^T + bias, exp, P@V, normalize (unchanged) ----
    bf16x8 aQ[2][2];
#pragma unroll
    for (int rt = 0; rt < 2; rt++)
#pragma unroll
        for (int s = 0; s < 2; s++)
            aQ[rt][s] = *reinterpret_cast<const bf16x8*>(
                &sQ[(wave * 32 + rt * 16 + l15) * 72 + s * 32 + quad * 8]);

    f32x4 accO[2][4];
    float rs[2][4];
#pragma unroll
    for (int rt = 0; rt < 2; rt++)
#pragma unroll
        for (int ct = 0; ct < 4; ct++) {
            f32x4 z = {0.0f, 0.0f, 0.0f, 0.0f};
            accO[rt][ct] = z;
            rs[rt][ct] = 0.0f;  // rs[rt][r]
        }

    ushort_t* sPw = sP + wave * (32 * 72);

    for (int jb = 0; jb < 4; jb++) {
        int kb = jb * 64;
        bf16x8 bK[4][2];
#pragma unroll
        for (int ctk = 0; ctk < 4; ctk++)
#pragma unroll
            for (int s = 0; s < 2; s++)
                bK[ctk][s] = *reinterpret_cast<const bf16x8*>(
                    &sK[(kb + ctk * 16 + l15) * 72 + s * 32 + quad * 8]);

#pragma unroll
        for (int ctk = 0; ctk < 4; ctk++) {
            float tcol = stb[kb + ctk * 16 + l15];
#pragma unroll
            for (int rt = 0; rt < 2; rt++) {
                f32x4 sa = {0.0f, 0.0f, 0.0f, 0.0f};
                sa = __builtin_amdgcn_mfma_f32_16x16x32_bf16(aQ[rt][0], bK[ctk][0], sa, 0, 0, 0);
                sa = __builtin_amdgcn_mfma_f32_16x16x32_bf16(aQ[rt][1], bK[ctk][1], sa, 0, 0, 0);
                int rl0 = rt * 16 + quad * 4;
#pragma unroll
                for (int r = 0; r < 4; r++) {
                    float pexp = __expf(sa[r] + tcol);  // |S|<~5, masked ~ -100, safe in f32
                    rs[rt][r] += pexp;
                    sPw[(rl0 + r) * 72 + ctk * 16 + l15] = f2bf(pexp);
                }
            }
        }

        // P @ V over this key block (wave-private P, same-wave LDS ordering, no barrier)
#pragma unroll
        for (int s = 0; s < 2; s++) {
            bf16x8 aP[2];
#pragma unroll
            for (int rt = 0; rt < 2; rt++)
                aP[rt] = *reinterpret_cast<const bf16x8*>(
                    &sPw[(rt * 16 + l15) * 72 + s * 32 + quad * 8]);
#pragma unroll
            for (int ct = 0; ct < 4; ct++) {
                bf16x8 bV = *reinterpret_cast<const bf16x8*>(
                    &sVt[(ct * 16 + l15) * 264 + kb + s * 32 + quad * 8]);
#pragma unroll
                for (int rt = 0; rt < 2; rt++)
                    accO[rt][ct] =
                        __builtin_amdgcn_mfma_f32_16x16x32_bf16(aP[rt], bV, accO[rt][ct], 0, 0, 0);
            }
        }
    }

    // Row sums: butterfly over the 16 lanes sharing a quad
    float inv_[2][4];
#pragma unroll
    for (int rt = 0; rt < 2; rt++)
#pragma unroll
        for (int r = 0; r < 4; r++) {
            float v = rs[rt][r];
            v += __shfl_xor(v, 1, 64);
            v += __shfl_xor(v, 2, 64);
            v += __shfl_xor(v, 4, 64);
            v += __shfl_xor(v, 8, 64);
            inv_[rt][r] = 1.0f / v;
        }

#pragma unroll
    for (int rt = 0; rt < 2; rt++)
#pragma unroll
        for (int ct = 0; ct < 4; ct++)
#pragma unroll
            for (int r = 0; r < 4; r++) {
                int m = wave * 32 + rt * 16 + quad * 4 + r;
                xout[((size_t)(kc * 256 + m)) * 512 + h * 64 + ct * 16 + l15] =
                    f2bf(accO[rt][ct][r] * inv_[rt][r]);
            }
}
__global__ __launch_bounds__(512, 2) void kattn_bf(const ushort_t* __restrict__ featb,
                                                   const ushort_t* __restrict__ qkv_wt,
                                                   const float* __restrict__ qb,
                                                   const float* __restrict__ tb, ushort_t* __restrict__ xout) {
    __shared__ ushort_t sQ[256 * 72];
    __shared__ ushort_t sK[256 * 72];
    __shared__ ushort_t sVt[64 * 264];
    __shared__ ushort_t sP[8 * 32 * 72];
    __shared__ float stb[256];
    kattn_body<false>(featb, qkv_wt, qb, tb, xout, sQ, sK, sVt, sP, stb);
}
__global__ __launch_bounds__(512, 2) void kattn_dyn(const int* __restrict__ dt, const void* __restrict__ feat,
                                                    const ushort_t* __restrict__ qkv_wt,
                                                    const float* __restrict__ qb,
                                                    const float* __restrict__ tb, ushort_t* __restrict__ xout) {
    __shared__ ushort_t sQ[256 * 72];
    __shared__ ushort_t sK[256 * 72];
    __shared__ ushort_t sVt[64 * 264];
    __shared__ ushort_t sP[8 * 32 * 72];
    __shared__ float stb[256];
    if (dt[0]) kattn_body<false>(feat, qkv_wt, qb, tb, xout, sQ, sK, sVt, sP, stb);
    else       kattn_body<true>(feat, qkv_wt, qb, tb, xout, sQ, sK, sVt, sP, stb);
}

// ---------------- K4: out = x @ proj_w + proj_b ----------------
// proj_wt col-slice (128 x 512) staged through LDS (global_load_lds, dbuf),
// removing the 4x per-wave duplicated global gathers.
template <bool F32>
static __device__ __forceinline__ void kproj_body(const ushort_t* x, const ushort_t* proj_wt,
                                                  const float* pb, void* out, ushort_t* sW) {
    const int tid = threadIdx.x;
    const int lane = tid & 63;
    const int wave = tid >> 6;   // 0..3
    const int quad = lane >> 4;
    const int l15 = lane & 15;
    const int rowb = (blockIdx.x & 255) * 256 + wave * 64;
    const int colb = (blockIdx.x >> 8) * 128;
    char* ldsW = (char*)sW;

    // staging: 512 tasks = 128 rows x 4 chunks(16B); t1 = wave*64+lane, t2 = t1+256
    const int t1 = wave * 64 + lane;
    const int t2 = t1 + 256;
    const ushort_t* g1 = proj_wt + (size_t)(colb + (t1 >> 2)) * 512 + (t1 & 3) * 8;
    const ushort_t* g2 = proj_wt + (size_t)(colb + (t2 >> 2)) * 512 + (t2 & 3) * 8;

    f32x4 acc[4][8];
#pragma unroll
    for (int rt = 0; rt < 4; rt++)
#pragma unroll
        for (int ct = 0; ct < 8; ct++) {
            f32x4 z = {0.0f, 0.0f, 0.0f, 0.0f};
            acc[rt][ct] = z;
        }

    gload_lds16(g1, ldsW + wave * 1024);
    gload_lds16(g2, ldsW + 4096 + wave * 1024);
    __syncthreads();

#pragma unroll 2
    for (int c = 0; c < 16; c++) {
        const int cb = (c & 1) * 4096;           // u16 offset of current buf
        const int nbB = ((c + 1) & 1) * 8192;    // byte offset of next buf
        if (c < 15) {
            gload_lds16(g1 + (c + 1) * 32, ldsW + nbB + wave * 1024);
            gload_lds16(g2 + (c + 1) * 32, ldsW + nbB + 4096 + wave * 1024);
        }
        bf16x8 af[4];
#pragma unroll
        for (int rt = 0; rt < 4; rt++) {
            int m = rowb + rt * 16 + l15;
            af[rt] = *reinterpret_cast<const bf16x8*>(x + (size_t)m * 512 + c * 32 + quad * 8);
        }
        bf16x8 bw[8];
#pragma unroll
        for (int ct = 0; ct < 8; ct++)
            bw[ct] = *reinterpret_cast<const bf16x8*>(sW + cb + (ct * 16 + l15) * 32 + quad * 8);
#pragma unroll
        for (int ct = 0; ct < 8; ct++)
#pragma unroll
            for (int rt = 0; rt < 4; rt++)
                acc[rt][ct] = __builtin_amdgcn_mfma_f32_16x16x32_bf16(af[rt], bw[ct], acc[rt][ct], 0, 0, 0);
        __syncthreads();
    }

#pragma unroll
    for (int ct = 0; ct < 8; ct++) {
        int n = colb + ct * 16 + l15;
        float bias = pb[n];
#pragma unroll
        for (int rt = 0; rt < 4; rt++)
#pragma unroll
            for (int r = 0; r < 4; r++) {
                int m = rowb + rt * 16 + quad * 4 + r;
                float v = acc[rt][ct][r] + bias;
                if (F32) ((float*)out)[(size_t)m * 512 + n] = v;
                else     ((ushort_t*)out)[(size_t)m * 512 + n] = f2bf(v);
            }
    }
}
__global__ __launch_bounds__(256, 2) void kproj(const int* __restrict__ dt, const ushort_t* __restrict__ x,
                                                const ushort_t* __restrict__ proj_wt,
                                                const float* __restrict__ pb, void* __restrict__ out) {
    __shared__ ushort_t sW[2 * 128 * 32];
    if (dt[0]) kproj_body<false>(x, proj_wt, pb, out, sW);
    else       kproj_body<true>(x, proj_wt, pb, out, sW);
}

extern "C" void kernel_launch(void* const* d_in, const int* in_sizes, int n_in,
                              void* d_out, int out_size, void* d_ws, size_t ws_size,
                              hipStream_t stream) {
    (void)in_sizes; (void)n_in; (void)out_size;
    const void* pos    = d_in[0];
    const void* feat   = d_in[1];
    const void* qkv_w  = d_in[2];
    const void* qkv_b  = d_in[3];
    const void* pos_w  = d_in[4];
    // d_in[5] = pos_b: softmax-invariant (constant per attention row), intentionally unused
    const void* proj_w = d_in[6];
    const void* proj_b = d_in[7];
    const int* mask    = (const int*)d_in[8];

    char* ws = (char*)d_ws;
    int* pmax         = (int*)ws;                           // ints 0,1
    int* dtf          = (int*)ws + 2;                       // int 2: dtype flag
    float* qb         = (float*)(ws + 256);                 // 1536 f32
    float* pb         = (float*)(ws + 256 + 6144);          // 512 f32
    float* tb         = (float*)(ws + 16384);               // 65536*8 f32 = 2 MB
    ushort_t* qkv_wt  = (ushort_t*)(ws + 16384 + 2097152);  // 1536x512 bf16
    ushort_t* proj_wt = qkv_wt + 786432;                    // 512x512 bf16
    ushort_t* x       = proj_wt + 262144;                   // 65536x512 bf16 = 64 MB
    ushort_t* featb   = x + 33554432;                       // 65536x512 bf16 = 64 MB
    const size_t NEED = 16384 + 2097152 + 1572864 + 524288 + 67108864 + 67108864;
    const bool big = ws_size >= NEED;

    (void)hipMemsetAsync(ws, 0, 16, stream);
    kprobe<<<1, 64, 0, stream>>>((const ushort_t*)pos, dtf);
    kpos_max<<<256, 256, 0, stream>>>(dtf, pos, pmax);
    ktb<<<256, 256, 0, stream>>>(dtf, pos, pos_w, mask, pmax, tb);
    kbias<<<6, 256, 0, stream>>>(dtf, qkv_b, proj_b, qb, pb);
    ktrans<<<192, 256, 0, stream>>>(dtf, qkv_w, qkv_wt, 512, 1536);
    ktrans<<<64, 256, 0, stream>>>(dtf, proj_w, proj_wt, 512, 512);
    if (big) {
        kfeat<<<2048, 256, 0, stream>>>(dtf, feat, featb);
        kattn_bf<<<2048, 512, 0, stream>>>(featb, qkv_wt, qb, tb, x);
    } else {
        kattn_dyn<<<2048, 512, 0, stream>>>(dtf, feat, qkv_wt, qb, tb, x);
    }
    kproj<<<1024, 256, 0, stream>>>(dtf, x, proj_wt, pb, d_out);
}